// Round 3
// baseline (807.828 us; speedup 1.0000x reference)
//
#include <hip/hip_runtime.h>
#include <stdint.h>

typedef unsigned short u16;
typedef short bf16x8 __attribute__((ext_vector_type(8)));
typedef float f32x4 __attribute__((ext_vector_type(4)));

#define NTOK 100352      // B*H*W tokens
#define NWIN 2048        // B * 64 windows
#define CC 256
#define NHEAD 8
#define HDIM 32
#define NWT 49           // tokens per window
#define MLPD 1024
#define ATT_SCALE 0.17677669529663687f  // 32^-0.5

__device__ __forceinline__ u16 f2b(float f) {
  union { float f; uint32_t u; } c; c.f = f;
  return (u16)((c.u + 0x7fffu + ((c.u >> 16) & 1u)) >> 16);
}
__device__ __forceinline__ float b2f(u16 h) {
  union { uint32_t u; float f; } c; c.u = ((uint32_t)h) << 16;
  return c.f;
}

__device__ __forceinline__ void gload_lds16(const void* g, void* l) {
  __builtin_amdgcn_global_load_lds((const __attribute__((address_space(1))) void*)g,
                                   (__attribute__((address_space(3))) void*)l, 16, 0, 0);
}

// ---------------- weight convert + transpose: w[K][N] fp32 -> wT[N][K] bf16
__global__ __launch_bounds__(256) void wconv_k(const float* __restrict__ w,
                                               u16* __restrict__ wT, int K, int N) {
  int i = blockIdx.x * 256 + threadIdx.x;
  if (i < K * N) {
    int k = i / N, n = i % N;
    wT[(size_t)n * K + k] = f2b(w[i]);
  }
}

// ---------------- relative-position bias LUT: lut[h][m][n] (64x64 padded, 0 outside 49)
__global__ __launch_bounds__(256) void bias_lut_k(const float* __restrict__ rpb,
                                                  float* __restrict__ lut) {
  int i = blockIdx.x * 256 + threadIdx.x;
  if (i >= 8 * 64 * 64) return;
  int h = i >> 12, m = (i >> 6) & 63, n = i & 63;
  float v = 0.f;
  if (m < 49 && n < 49) {
    int i1 = n / 7, j1 = n % 7;   // query coords
    int i2 = m / 7, j2 = m % 7;   // key coords
    v = rpb[((i1 - i2 + 6) * 13 + (j1 - j2 + 6)) * 8 + h];
  }
  lut[i] = v;
}

// ---------------- LN (+ optional shift/window-partition) -> bf16 tokens
template<bool PART>
__global__ __launch_bounds__(256)
void ln_k(const float* __restrict__ x, const float* __restrict__ g,
          const float* __restrict__ be, u16* __restrict__ out) {
  int token = blockIdx.x * 4 + (threadIdx.x >> 6);
  int lane = threadIdx.x & 63;
  size_t src;
  if (PART) {
    int win = token / 49, nn = token % 49;
    int b = win >> 6, wh = (win >> 3) & 7, ww = win & 7;
    int i = nn / 7, j = nn % 7;
    int h = wh * 7 + i + 3; if (h >= 56) h -= 56;
    int w = ww * 7 + j + 3; if (w >= 56) w -= 56;
    src = ((size_t)((b * 56 + h) * 56 + w)) * CC;
  } else {
    src = (size_t)token * CC;
  }
  f32x4 v = *(const f32x4*)&x[src + lane * 4];
  float s1 = v[0] + v[1] + v[2] + v[3];
  float s2 = v[0]*v[0] + v[1]*v[1] + v[2]*v[2] + v[3]*v[3];
#pragma unroll
  for (int o = 32; o; o >>= 1) { s1 += __shfl_xor(s1, o); s2 += __shfl_xor(s2, o); }
  float mean = s1 * (1.f / 256.f);
  float var = s2 * (1.f / 256.f) - mean * mean;
  float rstd = rsqrtf(var + 1e-5f);
  f32x4 gv = *(const f32x4*)&g[lane * 4];
  f32x4 bv = *(const f32x4*)&be[lane * 4];
  float y0 = (v[0]-mean)*rstd*gv[0] + bv[0];
  float y1 = (v[1]-mean)*rstd*gv[1] + bv[1];
  float y2 = (v[2]-mean)*rstd*gv[2] + bv[2];
  float y3 = (v[3]-mean)*rstd*gv[3] + bv[3];
  uint32_t lo = f2b(y0) | ((uint32_t)f2b(y1) << 16);
  uint32_t hi = f2b(y2) | ((uint32_t)f2b(y3) << 16);
  *(uint2*)&out[(size_t)token * CC + lane * 4] = make_uint2(lo, hi);
}

// ---------------- GEMM: C = A(MxK,bf16) * BT(NxK,bf16)^T + bias, epilogue variants
#define BM 128
#define BN 128
#define BK 32
enum { EPI_QKV = 0, EPI_PROJ = 1 };

template<int EPI>
__global__ __launch_bounds__(256)
void gemm_k(const u16* __restrict__ A, const u16* __restrict__ BT,
            const float* __restrict__ bias, int K,
            void* __restrict__ p0, const void* __restrict__ p1) {
  __shared__ u16 aL[BM * BK];
  __shared__ u16 bL[BN * BK];
  const int tid = threadIdx.x;
  const int lane = tid & 63;
  const int wv = tid >> 6;
  const int wm = wv >> 1, wn = wv & 1;

  // T1: XCD-aware block swizzle (nwg divisible by 8 for all our grids)
  int bx = blockIdx.x, by = blockIdx.y;
  {
    int nwg = gridDim.x * gridDim.y;
    int lin = by * gridDim.x + bx;
    int wg = (lin & 7) * (nwg >> 3) + (lin >> 3);
    bx = wg % gridDim.x;
    by = wg / gridDim.x;
  }
  const long m0 = (long)by * BM;
  const int n0 = bx * BN;

  f32x4 acc[4][4] = {};

  const int r15 = lane & 15;
  const int kc = lane >> 4;
  const int rcsw = kc ^ ((r15 >> 1) & 3);   // swizzled 16B-chunk for ds_read

  for (int kt = 0; kt < K; kt += BK) {
#pragma unroll
    for (int it = 0; it < 2; ++it) {
      int slot = tid + 256 * it;
      int row = slot >> 2, c = slot & 3;
      int cs = c ^ ((row >> 1) & 3);
      gload_lds16(&A[(m0 + row) * K + kt + cs * 8], &aL[slot * 8]);
    }
#pragma unroll
    for (int it = 0; it < 2; ++it) {
      int slot = tid + 256 * it;
      int row = slot >> 2, c = slot & 3;
      int cs = c ^ ((row >> 1) & 3);
      gload_lds16(&BT[(size_t)(n0 + row) * K + kt + cs * 8], &bL[slot * 8]);
    }
    __syncthreads();
    bf16x8 af[4], bfr[4];
#pragma unroll
    for (int m = 0; m < 4; ++m)
      af[m] = *(const bf16x8*)&aL[(wm * 64 + m * 16 + r15) * BK + rcsw * 8];
#pragma unroll
    for (int n = 0; n < 4; ++n)
      bfr[n] = *(const bf16x8*)&bL[(wn * 64 + n * 16 + r15) * BK + rcsw * 8];
#pragma unroll
    for (int m = 0; m < 4; ++m)
#pragma unroll
      for (int n = 0; n < 4; ++n)
        acc[m][n] = __builtin_amdgcn_mfma_f32_16x16x32_bf16(af[m], bfr[n], acc[m][n], 0, 0, 0);
    __syncthreads();
  }

  // epilogue: C/D layout col = lane&15, row = (lane>>4)*4 + j
#pragma unroll
  for (int m = 0; m < 4; ++m) {
    int rb = wm * 64 + m * 16 + (lane >> 4) * 4;
#pragma unroll
    for (int n = 0; n < 4; ++n) {
      int col = n0 + wn * 64 + n * 16 + (lane & 15);
      float bv = bias[col];
#pragma unroll
      for (int j = 0; j < 4; ++j) {
        int grow = (int)m0 + rb + j;
        float v = acc[m][n][j] + bv;
        if (EPI == EPI_QKV) {
          v = fmaxf(v, 0.f);
          int s = col >> 8, head = (col >> 5) & 7, d = col & 31;
          if (s == 0) v *= ATT_SCALE;   // fold softmax scale into q
          int win = grow / 49, nn = grow % 49;
          u16* dst = (u16*)p0 + (size_t)s * ((size_t)NTOK * CC);
          dst[(((size_t)(win * NHEAD + head)) * NWT + nn) * HDIM + d] = f2b(v);
        } else {  // EPI_PROJ: reverse shift + residual, fp32 out
          int win = grow / 49, nn = grow % 49;
          int b = win >> 6, wh = (win >> 3) & 7, ww = win & 7;
          int i = nn / 7, jj = nn % 7;
          int h = wh * 7 + i + 3; if (h >= 56) h -= 56;
          int w = ww * 7 + jj + 3; if (w >= 56) w -= 56;
          size_t pix = (size_t)((b * 56 + h) * 56 + w);
          float o = ((const float*)p1)[pix * CC + col] + v;
          ((float*)p0)[pix * CC + col] = o;
        }
      }
    }
  }
}

// ---------------- fused MLP: out = x2 + gelu(xn @ fc1 + b1) @ fc2 + b2
// Stage 1 computes S^T = fc1T·xn^T (both fragments K-contiguous from global/L2;
// C-layout gives each lane 4 consecutive mlp-cols -> packed b64 LDS writes).
// Stage 2 reads h back as b128 A-fragments, MFMAs vs fc2T. h never touches HBM.
#define LDH 136   // u16 pitch of h chunk rows (128 + 8 pad)
__global__ __launch_bounds__(512, 2)
void mlp_k(const u16* __restrict__ xn, const u16* __restrict__ fc1T,
           const u16* __restrict__ fc2T, const float* __restrict__ b1,
           const float* __restrict__ b2, const float* __restrict__ x2,
           float* __restrict__ outp) {
  __shared__ u16 hL[2][128][LDH];
  const int tid = threadIdx.x;
  const int lane = tid & 63;
  const int wv = tid >> 6;
  const int c = lane & 15;
  const int g = lane >> 4;
  const long m0 = (long)blockIdx.x * 128;

  const int wn1 = wv >> 2;     // stage1: n-half (0..1), 64 mlp-cols
  const int wr1 = wv & 3;      // stage1: r-quarter (0..3), 32 rows
  const int wr2 = wv >> 2;     // stage2: r-half (0..1), 64 rows
  const int wn2 = wv & 3;      // stage2: nout-quarter (0..3), 64 cols

  // hoist xn B-fragments (reused by all 8 chunks): rows wr1*32 + rt*16 + c
  bf16x8 xnf[8][2];
#pragma unroll
  for (int kk = 0; kk < 8; ++kk)
#pragma unroll
    for (int rt = 0; rt < 2; ++rt)
      xnf[kk][rt] = *(const bf16x8*)&xn[(m0 + wr1 * 32 + rt * 16 + c) * 256 + kk * 32 + g * 8];

  f32x4 oacc[4][4] = {};

  for (int hc = 0; hc < 8; ++hc) {
    const int nbase = hc * 128 + wn1 * 64;
    f32x4 acc1[4][2] = {};
#pragma unroll
    for (int kk = 0; kk < 8; ++kk) {
      bf16x8 af[4];
#pragma unroll
      for (int nt = 0; nt < 4; ++nt)
        af[nt] = *(const bf16x8*)&fc1T[(size_t)(nbase + nt * 16 + c) * 256 + kk * 32 + g * 8];
#pragma unroll
      for (int nt = 0; nt < 4; ++nt)
#pragma unroll
        for (int rt = 0; rt < 2; ++rt)
          acc1[nt][rt] = __builtin_amdgcn_mfma_f32_16x16x32_bf16(af[nt], xnf[kk][rt], acc1[nt][rt], 0, 0, 0);
    }
    // bias + exact GELU -> h chunk in LDS (S^T layout: lane holds 4 consecutive n at fixed r)
    u16(*hb)[LDH] = hL[hc & 1];
#pragma unroll
    for (int nt = 0; nt < 4; ++nt) {
      f32x4 bv = *(const f32x4*)&b1[nbase + nt * 16 + g * 4];
#pragma unroll
      for (int rt = 0; rt < 2; ++rt) {
        int r = wr1 * 32 + rt * 16 + c;
        float v0 = acc1[nt][rt][0] + bv[0];
        float v1 = acc1[nt][rt][1] + bv[1];
        float v2 = acc1[nt][rt][2] + bv[2];
        float v3 = acc1[nt][rt][3] + bv[3];
        v0 = 0.5f * v0 * (1.f + erff(v0 * 0.70710678118654752f));
        v1 = 0.5f * v1 * (1.f + erff(v1 * 0.70710678118654752f));
        v2 = 0.5f * v2 * (1.f + erff(v2 * 0.70710678118654752f));
        v3 = 0.5f * v3 * (1.f + erff(v3 * 0.70710678118654752f));
        uint32_t w0 = (uint32_t)f2b(v0) | ((uint32_t)f2b(v1) << 16);
        uint32_t w1 = (uint32_t)f2b(v2) | ((uint32_t)f2b(v3) << 16);
        *(uint2*)&hb[r][wn1 * 64 + nt * 16 + g * 4] = make_uint2(w0, w1);
      }
    }
    __syncthreads();   // single barrier per chunk (double-buffered h)
    // stage 2: oacc += h_chunk @ fc2T[:, hc*128..]
#pragma unroll
    for (int kk = 0; kk < 4; ++kk) {
      bf16x8 ha[4], wb[4];
#pragma unroll
      for (int rt = 0; rt < 4; ++rt)
        ha[rt] = *(const bf16x8*)&hb[wr2 * 64 + rt * 16 + c][kk * 32 + g * 8];
#pragma unroll
      for (int nt = 0; nt < 4; ++nt)
        wb[nt] = *(const bf16x8*)&fc2T[(size_t)(wn2 * 64 + nt * 16 + c) * 1024 + hc * 128 + kk * 32 + g * 8];
#pragma unroll
      for (int rt = 0; rt < 4; ++rt)
#pragma unroll
        for (int nt = 0; nt < 4; ++nt)
          oacc[rt][nt] = __builtin_amdgcn_mfma_f32_16x16x32_bf16(ha[rt], wb[nt], oacc[rt][nt], 0, 0, 0);
    }
  }

  // epilogue: out = x2 + oacc + b2
#pragma unroll
  for (int rt = 0; rt < 4; ++rt) {
    long rb = m0 + wr2 * 64 + rt * 16 + g * 4;
#pragma unroll
    for (int nt = 0; nt < 4; ++nt) {
      int col = wn2 * 64 + nt * 16 + c;
      float bv = b2[col];
#pragma unroll
      for (int j = 0; j < 4; ++j) {
        size_t idx = (size_t)(rb + j) * CC + col;
        outp[idx] = x2[idx] + oacc[rt][nt][j] + bv;
      }
    }
  }
}

// ---------------- MFMA window attention: 1 wave = 1 (window, head), 4 waves/block
__global__ __launch_bounds__(256)
void attn_mfma_k(const u16* __restrict__ q, const u16* __restrict__ k2,
                 const u16* __restrict__ v2, const float* __restrict__ lut,
                 u16* __restrict__ out) {
  __shared__ u16 P_lds[4][64 * 72];
  const int tid = threadIdx.x;
  const int wv = tid >> 6;
  const int lane = tid & 63;
  const int c = lane & 15;
  const int g = lane >> 4;
  const int blk = blockIdx.x * 4 + wv;   // (window, head) id
  const int head = blk & 7;
  const int win = blk >> 3;
  const int wimg = win & 63;
  const int wh = wimg >> 3, ww = wimg & 7;
  const size_t base = (size_t)blk * (NWT * HDIM);
  u16* Pw = P_lds[wv];

  bf16x8 kf[4], qf[4];
#pragma unroll
  for (int t = 0; t < 4; ++t) {
    kf[t] = *(const bf16x8*)&k2[base + (size_t)(t * 16 + c) * HDIM + g * 8];
    qf[t] = *(const bf16x8*)&q [base + (size_t)(t * 16 + c) * HDIM + g * 8];
  }
  bf16x8 vf[2][2];
#pragma unroll
  for (int kcc = 0; kcc < 2; ++kcc)
#pragma unroll
    for (int td = 0; td < 2; ++td)
#pragma unroll
      for (int jj = 0; jj < 8; ++jj) {
        int m = kcc * 32 + g * 8 + jj;
        m = m < 49 ? m : 48;
        vf[kcc][td][jj] = (short)v2[base + (size_t)m * HDIM + td * 16 + c];
      }

  f32x4 acc[4][4] = {};
#pragma unroll
  for (int tm = 0; tm < 4; ++tm)
#pragma unroll
    for (int tn = 0; tn < 4; ++tn)
      acc[tm][tn] = __builtin_amdgcn_mfma_f32_16x16x32_bf16(kf[tm], qf[tn], acc[tm][tn], 0, 0, 0);

  const float* lrow = &lut[(size_t)head * 64 * 64];
  int Ln[4];
#pragma unroll
  for (int tn = 0; tn < 4; ++tn) {
    int n = tn * 16 + c;
    int i1 = (n * 9363) >> 16;
    int j1 = n - i1 * 7;
    int rh = (wh < 7) ? 0 : (i1 < 4 ? 1 : 2);
    int rw = (ww < 7) ? 0 : (j1 < 4 ? 1 : 2);
    Ln[tn] = rh * 3 + rw;
  }
  float colmax[4] = {0.f, 0.f, 0.f, 0.f};
#pragma unroll
  for (int tm = 0; tm < 4; ++tm)
#pragma unroll
    for (int j = 0; j < 4; ++j) {
      int m = tm * 16 + g * 4 + j;
      int i2 = (m * 9363) >> 16;
      int j2 = m - i2 * 7;
      int rh = (wh < 7) ? 0 : (i2 < 4 ? 1 : 2);
      int rw = (ww < 7) ? 0 : (j2 < 4 ? 1 : 2);
      int Lm = rh * 3 + rw;
#pragma unroll
      for (int tn = 0; tn < 4; ++tn) {
        float s = acc[tm][tn][j] + lrow[m * 64 + tn * 16 + c];
        s = fmaxf(s, 0.f);
        if (Lm != Ln[tn]) s = 0.f;
        acc[tm][tn][j] = s;
        colmax[tn] = fmaxf(colmax[tn], s);
      }
    }
#pragma unroll
  for (int tn = 0; tn < 4; ++tn) {
    colmax[tn] = fmaxf(colmax[tn], __shfl_xor(colmax[tn], 16));
    colmax[tn] = fmaxf(colmax[tn], __shfl_xor(colmax[tn], 32));
  }
  float colsum[4] = {0.f, 0.f, 0.f, 0.f};
#pragma unroll
  for (int tm = 0; tm < 4; ++tm)
#pragma unroll
    for (int j = 0; j < 4; ++j) {
      int m = tm * 16 + g * 4 + j;
      bool mvalid = (m < NWT);
#pragma unroll
      for (int tn = 0; tn < 4; ++tn) {
        float e = mvalid ? __expf(acc[tm][tn][j] - colmax[tn]) : 0.f;
        acc[tm][tn][j] = e;
        colsum[tn] += e;
      }
    }
#pragma unroll
  for (int tn = 0; tn < 4; ++tn) {
    colsum[tn] += __shfl_xor(colsum[tn], 16);
    colsum[tn] += __shfl_xor(colsum[tn], 32);
    colsum[tn] = 1.f / colsum[tn];
  }

#pragma unroll
  for (int tn = 0; tn < 4; ++tn) {
    int n = tn * 16 + c;
#pragma unroll
    for (int tm = 0; tm < 4; ++tm) {
      float r = colsum[tn];
      uint32_t w0 = (uint32_t)f2b(acc[tm][tn][0] * r) | ((uint32_t)f2b(acc[tm][tn][1] * r) << 16);
      uint32_t w1 = (uint32_t)f2b(acc[tm][tn][2] * r) | ((uint32_t)f2b(acc[tm][tn][3] * r) << 16);
      *(uint2*)&Pw[n * 72 + tm * 16 + g * 4] = make_uint2(w0, w1);
    }
  }

  f32x4 oacc[4][2] = {};
#pragma unroll
  for (int kcc = 0; kcc < 2; ++kcc) {
    bf16x8 pf[4];
#pragma unroll
    for (int tr = 0; tr < 4; ++tr)
      pf[tr] = *(const bf16x8*)&Pw[(tr * 16 + c) * 72 + kcc * 32 + g * 8];
#pragma unroll
    for (int tr = 0; tr < 4; ++tr)
#pragma unroll
      for (int td = 0; td < 2; ++td)
        oacc[tr][td] = __builtin_amdgcn_mfma_f32_16x16x32_bf16(pf[tr], vf[kcc][td], oacc[tr][td], 0, 0, 0);
  }

#pragma unroll
  for (int tr = 0; tr < 4; ++tr)
#pragma unroll
    for (int j = 0; j < 4; ++j) {
      int n = tr * 16 + g * 4 + j;
      if (n < NWT) {
#pragma unroll
        for (int td = 0; td < 2; ++td) {
          int d = td * 16 + c;
          out[((size_t)(win * NWT + n)) * CC + head * HDIM + d] =
              f2b(fmaxf(oacc[tr][td][j], 0.f));
        }
      }
    }
}

// ---------------- launch
extern "C" void kernel_launch(void* const* d_in, const int* in_sizes, int n_in,
                              void* d_out, int out_size, void* d_ws, size_t ws_size,
                              hipStream_t stream) {
  const float* x      = (const float*)d_in[0];
  const float* gamma1 = (const float*)d_in[1];
  const float* beta1  = (const float*)d_in[2];
  const float* w_qkv  = (const float*)d_in[3];
  const float* b_qkv  = (const float*)d_in[4];
  const float* rpb    = (const float*)d_in[5];
  const float* w_proj = (const float*)d_in[6];
  const float* b_proj = (const float*)d_in[7];
  const float* gamma2 = (const float*)d_in[8];
  const float* beta2  = (const float*)d_in[9];
  const float* w_fc1  = (const float*)d_in[10];
  const float* b_fc1  = (const float*)d_in[11];
  const float* w_fc2  = (const float*)d_in[12];
  const float* b_fc2  = (const float*)d_in[13];
  float* out = (float*)d_out;

  char* ws = (char*)d_ws;
  size_t off = 0;
  auto alloc = [&](size_t bytes) { void* p = ws + off; off = (off + bytes + 255) & ~(size_t)255; return p; };

  u16* wqkvT = (u16*)alloc(768 * 256 * 2);
  u16* wprojT = (u16*)alloc(256 * 256 * 2);
  u16* wfc1T = (u16*)alloc(1024 * 256 * 2);
  u16* wfc2T = (u16*)alloc(256 * 1024 * 2);
  float* lut = (float*)alloc(8 * 64 * 64 * 4);
  // region2: xw -> attn_out -> xn2 (lifetimes disjoint)
  u16* region2 = (u16*)alloc((size_t)NTOK * CC * 2);
  // region1: q|k|v (3x 51.4MB); after attention reused as x2 (fp32, 102.8MB)
  char* region1 = (char*)alloc((size_t)3 * NTOK * CC * 2);

  u16* xw = region2;
  u16* qb = (u16*)region1;
  u16* kb = qb + (size_t)NTOK * CC;
  u16* vb = kb + (size_t)NTOK * CC;
  u16* attn_out = region2;
  float* x2 = (float*)region1;
  u16* xn2 = region2;

  if (ws_size < off) return;  // insufficient scratch: fail visibly

  wconv_k<<<(256 * 768 + 255) / 256, 256, 0, stream>>>(w_qkv, wqkvT, 256, 768);
  wconv_k<<<(256 * 256 + 255) / 256, 256, 0, stream>>>(w_proj, wprojT, 256, 256);
  wconv_k<<<(256 * 1024 + 255) / 256, 256, 0, stream>>>(w_fc1, wfc1T, 256, 1024);
  wconv_k<<<(1024 * 256 + 255) / 256, 256, 0, stream>>>(w_fc2, wfc2T, 1024, 256);
  bias_lut_k<<<(8 * 64 * 64) / 256, 256, 0, stream>>>(rpb, lut);

  // LN1 + shift + partition
  ln_k<true><<<NTOK / 4, 256, 0, stream>>>(x, gamma1, beta1, xw);

  // QKV GEMM: M=100352, N=768, K=256 (XCD-swizzled)
  gemm_k<EPI_QKV><<<dim3(768 / BN, NTOK / BM), 256, 0, stream>>>(
      xw, wqkvT, b_qkv, 256, (void*)qb, nullptr);

  // fused MFMA window attention: 1 wave per (window, head)
  attn_mfma_k<<<NWIN * NHEAD / 4, 256, 0, stream>>>(qb, kb, vb, lut, attn_out);

  // proj GEMM + reverse shift + residual: M=100352, N=256, K=256
  gemm_k<EPI_PROJ><<<dim3(256 / BN, NTOK / BM), 256, 0, stream>>>(
      attn_out, wprojT, b_proj, 256, (void*)x2, (const void*)x);

  // LN2
  ln_k<false><<<NTOK / 4, 256, 0, stream>>>(x2, gamma2, beta2, xn2);

  // fused MLP (fc1 + GELU + fc2 + residual), h never hits HBM
  mlp_k<<<NTOK / 128, 512, 0, stream>>>(xn2, wfc1T, wfc2T, b_fc1, b_fc2, x2, out);
}